// Round 2
// baseline (343.627 us; speedup 1.0000x reference)
//
#include <hip/hip_runtime.h>
#include <stdint.h>

typedef __bf16 bf16x8 __attribute__((ext_vector_type(8)));
typedef float  f32x4  __attribute__((ext_vector_type(4)));

#define DEV __device__ __forceinline__

constexpr int Bc = 4, S = 2048, D = 1024, Hh = 16, DH = 64;
constexpr int Kdim = 1024;   // inner K of both GEMMs

DEV unsigned short f2bf(float f) {
    uint32_t u = __builtin_bit_cast(uint32_t, f);
    u += 0x7fff + ((u >> 16) & 1);   // RNE
    return (unsigned short)(u >> 16);
}
DEV bf16x8 ld8(const unsigned short* p) {
    uint4 u = *(const uint4*)p;
    return __builtin_bit_cast(bf16x8, u);
}
DEV uint4 pack8(float4 a, float4 b) {
    union { uint4 u; unsigned short s[8]; } r;
    r.s[0] = f2bf(a.x); r.s[1] = f2bf(a.y); r.s[2] = f2bf(a.z); r.s[3] = f2bf(a.w);
    r.s[4] = f2bf(b.x); r.s[5] = f2bf(b.y); r.s[6] = f2bf(b.z); r.s[7] = f2bf(b.w);
    return r.u;
}

// async global->LDS, 16B per lane. LDS dest is wave-uniform base + lane*16 (HW).
DEV void gl16(const void* g, void* l) {
    __builtin_amdgcn_global_load_lds((__attribute__((address_space(1))) void*)g,
                                     (__attribute__((address_space(3))) void*)l,
                                     16, 0, 0);
}

// ---------- weight transpose + cvt (f32 [rows][cols] -> bf16 [cols][rows]) ------
__global__ __launch_bounds__(256) void transpose_cvt(const float* __restrict__ in,
                                                     unsigned short* __restrict__ out,
                                                     int rows, int cols) {
    __shared__ float t[32][33];
    int tx = threadIdx.x & 31, ty = threadIdx.x >> 5;  // 32 x 8
    int c = blockIdx.x * 32 + tx;
    int rbase = blockIdx.y * 32;
    for (int rr = 0; rr < 32; rr += 8)
        t[ty + rr][tx] = in[(size_t)(rbase + ty + rr) * cols + c];
    __syncthreads();
    int orbase = blockIdx.x * 32;
    for (int rr = 0; rr < 32; rr += 8)
        out[(size_t)(orbase + ty + rr) * rows + rbase + tx] = f2bf(t[tx][ty + rr]);
}

// ---------- x f32 -> bf16, once --------------------------------------------------
__global__ __launch_bounds__(256) void cvt_bf16(const float* __restrict__ in,
                                                unsigned short* __restrict__ out) {
    size_t i = (size_t)blockIdx.x * 256 + threadIdx.x;   // 8 elems per thread, exact grid
    const float4* p = (const float4*)(in + i * 8);
    float4 a = p[0], b = p[1];
    *(uint4*)(out + i * 8) = pack8(a, b);
}

// ---------- GEMM: C[M,N] = A_bf16[M,K] * Bt_bf16[N,K]^T + bias_f32 --------------
// 2-phase pipeline: double-buffered 8KB tiles, next tile's global_load_lds issued
// BEFORE computing current, raw s_barrier + counted s_waitcnt vmcnt(4) so the
// prefetch stays in flight across the barrier (T3-min + T4).
// mode 0: coalesced LDS-repacked scatter into q/k [B,H,S,DH] and V^T [B,H,DH,S]
// mode 1: write f32 outf [M,N] directly
__global__ __launch_bounds__(256, 5) void gemm_bt(const unsigned short* __restrict__ A,
                                                  const unsigned short* __restrict__ Bt,
                                                  const float* __restrict__ bias,
                                                  int mode,
                                                  unsigned short* __restrict__ qo,
                                                  unsigned short* __restrict__ ko,
                                                  unsigned short* __restrict__ vo,
                                                  float* __restrict__ outf) {
    __shared__ __align__(16) unsigned short sh[4][4096];  // [0..1]=A dbuf, [2..3]=B dbuf (32KB)
    const int tid = threadIdx.x;
    const int wave = tid >> 6, lane = tid & 63, g = lane >> 4, ln = lane & 15;
    const int wm = wave >> 1, wn = wave & 1;          // 2x2 wave grid, 64x64 each
    const int m0 = blockIdx.y * 128, n0 = blockIdx.x * 128;

    f32x4 acc[4][4];
    for (int i = 0; i < 4; i++)
        for (int j = 0; j < 4; j++) acc[i][j] = f32x4{0.f, 0.f, 0.f, 0.f};

    // stage tile (4 gl16 per thread): A half + B half into buffer `buf`
#define STAGE_G(buf, k0)                                                            \
    _Pragma("unroll")                                                               \
    for (int c = 0; c < 2; c++) {                                                   \
        int L = c * 4096 + tid * 16;                                                \
        int row = L >> 6, colb = L & 63;                                            \
        gl16((const char*)A  + ((size_t)(m0 + row) * Kdim + (k0)) * 2 + colb,       \
             (char*)sh[buf]     + c * 4096 + wave * 1024);                          \
        gl16((const char*)Bt + ((size_t)(n0 + row) * Kdim + (k0)) * 2 + colb,       \
             (char*)sh[2 + (buf)] + c * 4096 + wave * 1024);                        \
    }

    STAGE_G(0, 0);
#pragma unroll 2
    for (int k0 = 0; k0 < Kdim; k0 += 32) {
        const int buf = (k0 >> 5) & 1;
        if (k0 + 32 < Kdim) {
            STAGE_G(buf ^ 1, k0 + 32);                          // prefetch next tile
            asm volatile("s_waitcnt vmcnt(4)" ::: "memory");    // current tile landed
        } else {
            asm volatile("s_waitcnt vmcnt(0)" ::: "memory");
        }
        __builtin_amdgcn_s_barrier();                           // all waves' deposits visible
        const unsigned short* As = sh[buf];
        const unsigned short* Bs = sh[2 + buf];
        bf16x8 af[4], bfr[4];
        for (int t = 0; t < 4; t++) af[t]  = ld8(As + (wm * 64 + t * 16 + ln) * 32 + g * 8);
        for (int t = 0; t < 4; t++) bfr[t] = ld8(Bs + (wn * 64 + t * 16 + ln) * 32 + g * 8);
        for (int mt = 0; mt < 4; mt++)
            for (int nt = 0; nt < 4; nt++)
                acc[mt][nt] = __builtin_amdgcn_mfma_f32_16x16x32_bf16(af[mt], bfr[nt], acc[mt][nt], 0, 0, 0);
        __builtin_amdgcn_s_barrier();                           // reads done before overwrite
        asm volatile("" ::: "memory");
    }
#undef STAGE_G

    if (mode == 0) {
        // repack through LDS (reuse all 32KB), then 8 coalesced uint4 stores/thread
        unsigned short* E = &sh[0][0];                 // [128][128] bf16 = 32KB
        const int which = n0 >> 10;                    // uniform per block (n0 mult of 128)
        const int hh0 = (n0 & 1023) >> 6;
        const int b = m0 >> 11;                        // uniform (m0 mult of 128)
        const int s0 = m0 & 2047;
#pragma unroll
        for (int nt = 0; nt < 4; nt++) {
            float bv = bias[n0 + wn * 64 + nt * 16 + ln];
#pragma unroll
            for (int mt = 0; mt < 4; mt++)
#pragma unroll
                for (int r = 0; r < 4; r++) {
                    int ml = wm * 64 + mt * 16 + g * 4 + r;
                    int nl = wn * 64 + nt * 16 + ln;
                    unsigned short v = f2bf(acc[mt][nt][r] + bv);
                    if (which == 2) E[nl * 128 + ml] = v;   // V-block stored transposed
                    else            E[ml * 128 + nl] = v;
                }
        }
        __syncthreads();
        if (which == 2) {
#pragma unroll
            for (int t = 0; t < 8; t++) {
                int e = (t * 256 + tid) * 8;
                int nl = e >> 7, mlo = e & 127;
                int dd = nl & 63, hh = hh0 + (nl >> 6);
                size_t dst = ((size_t)((b * 16 + hh) * 64 + dd)) * 2048 + s0 + mlo;  // V^T [bh][dd][s]
                *(uint4*)(vo + dst) = *(const uint4*)(E + e);
            }
        } else {
            unsigned short* qk = which ? ko : qo;
#pragma unroll
            for (int t = 0; t < 8; t++) {
                int e = (t * 256 + tid) * 8;
                int ml = e >> 7, nn = e & 127;
                int dd = nn & 63, hh = hh0 + (nn >> 6);
                size_t dst = ((size_t)((b * 16 + hh) * 2048 + s0 + ml)) * 64 + dd;   // [bh][s][dd]
                *(uint4*)(qk + dst) = *(const uint4*)(E + e);
            }
        }
    } else {
        // mode 1: direct f32 stores (lane-contiguous n -> 64B segments, OK)
        for (int mt = 0; mt < 4; mt++)
            for (int nt = 0; nt < 4; nt++)
                for (int r = 0; r < 4; r++) {
                    int m = m0 + wm * 64 + mt * 16 + g * 4 + r;
                    int n = n0 + wn * 64 + nt * 16 + ln;
                    outf[(size_t)m * 1024 + n] = acc[mt][nt][r] + bias[n];
                }
    }
}

// ---------- flash attention: single-buffer SPLIT pipeline -----------------------
// Ks is dead after QK^T, Vs dead after PV -> stage K(j+1) after the post-QK
// barrier (lands under softmax+PV) and V(j+1) after the post-PV barrier (lands
// under next iter's QK). Counted vmcnt(4) waits keep the other stage in flight.
__global__ __launch_bounds__(256, 3) void attn_fwd(const unsigned short* __restrict__ qg,
                                                   const unsigned short* __restrict__ kg,
                                                   const unsigned short* __restrict__ vtg,
                                                   unsigned short* __restrict__ og) {
    __shared__ __align__(16) unsigned short Ks[128 * 64];  // [kv][dh] swizzled
    __shared__ __align__(16) unsigned short Vs[64 * 128];  // [dh][kv] swizzled
    __shared__ __align__(16) unsigned short P [64 * 136];  // probs [q][kv], wave-private rows
    const int idx = blockIdx.x;
    const int qt = 31 - (idx >> 6);                        // heavy tiles dispatch first
    const int bh = idx & 63;                               // idx%8 = bh%8 -> same-bh same XCD
    const int b = bh >> 4, h = bh & 15;
    const size_t base = (size_t)bh * S * DH;
    const unsigned short* qp = qg + base;
    const char* kpb  = (const char*)(kg  + base);
    const char* vtpb = (const char*)(vtg + base);          // [DH][S] bytes: row stride 4096
    const int tid = threadIdx.x, wave = tid >> 6, lane = tid & 63;
    const int g = lane >> 4, ln = lane & 15;
    const int q0 = qt * 64, wq = wave * 16;                // wave's q rows [q0+wq, +16)
    const int jn = (qt >> 1) + 1;

    // Q B-frag (B-layout: n=ln -> q=q0+wq+ln; k=kc*32+g*8+j)
    bf16x8 qf[2];
    qf[0] = ld8(qp + (size_t)(q0 + wq + ln) * DH + g * 8);
    qf[1] = ld8(qp + (size_t)(q0 + wq + ln) * DH + 32 + g * 8);

#define STAGE_K(j)                                                                  \
    {   const char* kj = kpb + (size_t)(j) * (128 * DH * 2);                        \
        _Pragma("unroll")                                                           \
        for (int c = 0; c < 4; c++) {                                               \
            int L = c * 4096 + tid * 16;                                            \
            int kr = L >> 7, kcb = L & 127;                                         \
            gl16(kj + (size_t)kr * 128 + (kcb ^ ((kr & 7) << 4)),                   \
                 (char*)Ks + c * 4096 + wave * 1024);                               \
        }                                                                           \
    }
#define STAGE_V(j)                                                                  \
    {   const char* vj = vtpb + (j) * 256;                                          \
        _Pragma("unroll")                                                           \
        for (int c = 0; c < 4; c++) {                                               \
            int L = c * 4096 + tid * 16;                                            \
            int vr = L >> 8, vcb = L & 255;                                         \
            gl16(vj + (size_t)vr * 4096 + (vcb ^ ((vr & 15) << 4)),                 \
                 (char*)Vs + c * 4096 + wave * 1024);                               \
        }                                                                           \
    }

    STAGE_K(0);
    STAGE_V(0);

    f32x4 o_t[4];
#pragma unroll
    for (int dt = 0; dt < 4; dt++) o_t[dt] = f32x4{0.f, 0.f, 0.f, 0.f};
    float m_ = -1e30f, l_ = 0.f;

#pragma unroll 1
    for (int j = 0; j < jn; j++) {
        // entry outstanding: [K(j) x4, V(j) x4] -> wait the 4 oldest (K)
        asm volatile("s_waitcnt vmcnt(4)" ::: "memory");
        __builtin_amdgcn_s_barrier();                  // Ks(j) visible to all waves

        // ---- S^T = K*Q^T : st[mt] C-layout kv=mt*16+g*4+r, q-col=ln
        f32x4 st[8];
#pragma unroll
        for (int mt = 0; mt < 8; mt++) {
            int row = mt * 16 + ln;
            int sw = (row & 7) << 4;
            const char* kb2 = (const char*)Ks + row * 128;
            bf16x8 kf0 = ld8((const unsigned short*)(kb2 + ((g * 16) ^ sw)));
            bf16x8 kf1 = ld8((const unsigned short*)(kb2 + ((64 + g * 16) ^ sw)));
            f32x4 t = f32x4{0.f, 0.f, 0.f, 0.f};
            t = __builtin_amdgcn_mfma_f32_16x16x32_bf16(kf0, qf[0], t, 0, 0, 0);
            t = __builtin_amdgcn_mfma_f32_16x16x32_bf16(kf1, qf[1], t, 0, 0, 0);
            st[mt] = t;
        }
        __builtin_amdgcn_s_barrier();                  // all waves done reading Ks
        asm volatile("" ::: "memory");
        if (j + 1 < jn) STAGE_K(j + 1);                // K(j+1) in flight under softmax+PV

        if (j == jn - 1) {   // diagonal: mask kv_global > q_global
            int qgl = q0 + wq + ln;
#pragma unroll
            for (int mt = 0; mt < 8; mt++)
#pragma unroll
                for (int r = 0; r < 4; r++) {
                    int kvg = j * 128 + mt * 16 + g * 4 + r;
                    if (kvg > qgl) st[mt][r] = -3e38f;
                }
        }
        // ---- online softmax: q = ln is lane-resident; kv spread over (g, mt, r)
        f32x4 mm = st[0];
#pragma unroll
        for (int mt = 1; mt < 8; mt++)
#pragma unroll
            for (int e = 0; e < 4; e++) mm[e] = fmaxf(mm[e], st[mt][e]);
        float mx = fmaxf(fmaxf(mm[0], mm[1]), fmaxf(mm[2], mm[3]));
        mx = fmaxf(mx, __shfl_xor(mx, 16));
        mx = fmaxf(mx, __shfl_xor(mx, 32));
        float mnew = fmaxf(m_, mx);
        float alpha = __expf((m_ - mnew) * 0.125f);
        f32x4 sv = f32x4{0.f, 0.f, 0.f, 0.f};
#pragma unroll
        for (int mt = 0; mt < 8; mt++) {
            f32x4 pr;
#pragma unroll
            for (int e = 0; e < 4; e++) pr[e] = __expf((st[mt][e] - mnew) * 0.125f);
            st[mt] = pr;
            sv += pr;
        }
        float rs = (sv[0] + sv[1]) + (sv[2] + sv[3]);
        rs += __shfl_xor(rs, 16);
        rs += __shfl_xor(rs, 32);
        l_ = l_ * alpha + rs;
        m_ = mnew;

        // ---- pack P (truncate f32->bf16) into [q][kv] rows (wave-private)
#pragma unroll
        for (int mt = 0; mt < 8; mt++) {
            uint4 u = __builtin_bit_cast(uint4, st[mt]);
            uint2 w;
            w.x = (u.y & 0xFFFF0000u) | (u.x >> 16);
            w.y = (u.w & 0xFFFF0000u) | (u.z >> 16);
            *(uint2*)&P[(wq + ln) * 136 + mt * 16 + g * 4] = w;
        }
        // ---- rescale O^T (cols = q = ln)
#pragma unroll
        for (int dt = 0; dt < 4; dt++) o_t[dt] *= alpha;

        // V(j) landed? outstanding: [V(j) x4] (+K(j+1) x4 if staged)
        if (j + 1 < jn) asm volatile("s_waitcnt vmcnt(4)" ::: "memory");
        else            asm volatile("s_waitcnt vmcnt(0)" ::: "memory");
        __builtin_amdgcn_s_barrier();                  // Vs(j) visible to all waves

        // ---- O^T += V^T * P^T (A = V^T from swizzled LDS, B = P^T from wave rows)
#pragma unroll
        for (int kc = 0; kc < 4; kc++) {
            bf16x8 pf = ld8(&P[(wq + ln) * 136 + kc * 32 + g * 8]);
            bf16x8 vf[4];
#pragma unroll
            for (int dt = 0; dt < 4; dt++) {
                int row = dt * 16 + ln;
                vf[dt] = ld8((const unsigned short*)((const char*)Vs + row * 256 +
                             ((kc * 64 + g * 16) ^ ((row & 15) << 4))));
            }
#pragma unroll
            for (int dt = 0; dt < 4; dt++)
                o_t[dt] = __builtin_amdgcn_mfma_f32_16x16x32_bf16(vf[dt], pf, o_t[dt], 0, 0, 0);
        }
        __builtin_amdgcn_s_barrier();                  // all waves done reading Vs
        asm volatile("" ::: "memory");
        if (j + 1 < jn) STAGE_V(j + 1);                // V(j+1) in flight under next QK
    }
#undef STAGE_K
#undef STAGE_V

    // ---- epilogue: scale 1/l, transpose O^T via wave-private LDS, bf16 stores.
    float il = 1.f / l_;
#pragma unroll
    for (int dt = 0; dt < 4; dt++) o_t[dt] *= il;
    float* Ot = (float*)&P[wq * 136];
#pragma unroll
    for (int dt = 0; dt < 4; dt++)
        *(float4*)&Ot[ln * 68 + dt * 16 + g * 4] =
            float4{o_t[dt][0], o_t[dt][1], o_t[dt][2], o_t[dt][3]};
    // same-wave LDS RAW: DS ops are in-order per wave
#pragma unroll
    for (int i = 0; i < 4; i++) {
        float4 v = *(float4*)&Ot[(i * 4 + g) * 68 + ln * 4];
        uint2 w;
        w.x = (uint32_t)f2bf(v.x) | ((uint32_t)f2bf(v.y) << 16);
        w.y = (uint32_t)f2bf(v.z) | ((uint32_t)f2bf(v.w) << 16);
        *(uint2*)&og[((size_t)(b * S + q0 + wq + i * 4 + g)) * D + h * DH + ln * 4] = w;
    }
}

extern "C" void kernel_launch(void* const* d_in, const int* in_sizes, int n_in,
                              void* d_out, int out_size, void* d_ws, size_t ws_size,
                              hipStream_t stream) {
    (void)in_sizes; (void)n_in; (void)out_size; (void)ws_size;
    const float* x      = (const float*)d_in[0];  // [B,S,D] f32
    const float* w_attn = (const float*)d_in[1];  // [D,3D]  f32
    const float* b_attn = (const float*)d_in[2];  // [3D]    f32
    const float* w_proj = (const float*)d_in[3];  // [D,D]   f32
    const float* b_proj = (const float*)d_in[4];  // [D]     f32

    char* ws = (char*)d_ws;
    unsigned short* wattn_t = (unsigned short*)ws;                 // [3072][1024] bf16
    unsigned short* wproj_t = (unsigned short*)(ws + 6291456);     // [1024][1024] bf16
    unsigned short* xb      = (unsigned short*)(ws + 8388608);     // [B*S][D] bf16
    unsigned short* qb      = (unsigned short*)(ws + 25165824);    // [B,H,S,DH] bf16
    unsigned short* kb      = (unsigned short*)(ws + 41943040);
    unsigned short* vtb     = (unsigned short*)(ws + 58720256);    // [B,H,DH,S] bf16
    unsigned short* aob     = (unsigned short*)(ws + 75497472);    // [B,S,D] bf16

    transpose_cvt<<<dim3(96, 32), 256, 0, stream>>>(w_attn, wattn_t, 1024, 3072);
    transpose_cvt<<<dim3(32, 32), 256, 0, stream>>>(w_proj, wproj_t, 1024, 1024);
    cvt_bf16<<<dim3(4096), 256, 0, stream>>>(x, xb);
    gemm_bt<<<dim3(24, 64), 256, 0, stream>>>(xb, wattn_t, b_attn, 0, qb, kb, vtb, nullptr);
    attn_fwd<<<dim3(2048), 256, 0, stream>>>(qb, kb, vtb, aob);
    gemm_bt<<<dim3(8, 64), 256, 0, stream>>>(aob, wproj_t, b_proj, 1,
                                             nullptr, nullptr, nullptr, (float*)d_out);
}

// Round 3
// 284.047 us; speedup vs baseline: 1.2098x; 1.2098x over previous
//
#include <hip/hip_runtime.h>
#include <stdint.h>

typedef __bf16 bf16x8 __attribute__((ext_vector_type(8)));
typedef float  f32x4  __attribute__((ext_vector_type(4)));

#define DEV __device__ __forceinline__

constexpr int Bc = 4, S = 2048, D = 1024, Hh = 16, DH = 64;
constexpr int Kdim = 1024;   // inner K of both GEMMs

DEV unsigned short f2bf(float f) {
    uint32_t u = __builtin_bit_cast(uint32_t, f);
    u += 0x7fff + ((u >> 16) & 1);   // RNE
    return (unsigned short)(u >> 16);
}
DEV bf16x8 ld8(const unsigned short* p) {
    uint4 u = *(const uint4*)p;
    return __builtin_bit_cast(bf16x8, u);
}
DEV uint4 pack8(float4 a, float4 b) {
    union { uint4 u; unsigned short s[8]; } r;
    r.s[0] = f2bf(a.x); r.s[1] = f2bf(a.y); r.s[2] = f2bf(a.z); r.s[3] = f2bf(a.w);
    r.s[4] = f2bf(b.x); r.s[5] = f2bf(b.y); r.s[6] = f2bf(b.z); r.s[7] = f2bf(b.w);
    return r.u;
}

// async global->LDS, 16B per lane. LDS dest is wave-uniform base + lane*16 (HW).
DEV void gl16(const void* g, void* l) {
    __builtin_amdgcn_global_load_lds((__attribute__((address_space(1))) void*)g,
                                     (__attribute__((address_space(3))) void*)l,
                                     16, 0, 0);
}

// ---------- weight transpose + cvt (f32 [rows][cols] -> bf16 [cols][rows]) ------
__global__ __launch_bounds__(256) void transpose_cvt(const float* __restrict__ in,
                                                     unsigned short* __restrict__ out,
                                                     int rows, int cols) {
    __shared__ float t[32][33];
    int tx = threadIdx.x & 31, ty = threadIdx.x >> 5;  // 32 x 8
    int c = blockIdx.x * 32 + tx;
    int rbase = blockIdx.y * 32;
    for (int rr = 0; rr < 32; rr += 8)
        t[ty + rr][tx] = in[(size_t)(rbase + ty + rr) * cols + c];
    __syncthreads();
    int orbase = blockIdx.x * 32;
    for (int rr = 0; rr < 32; rr += 8)
        out[(size_t)(orbase + ty + rr) * rows + rbase + tx] = f2bf(t[tx][ty + rr]);
}

// ---------- x f32 -> bf16, once --------------------------------------------------
__global__ __launch_bounds__(256) void cvt_bf16(const float* __restrict__ in,
                                                unsigned short* __restrict__ out) {
    size_t i = (size_t)blockIdx.x * 256 + threadIdx.x;   // 8 elems per thread, exact grid
    const float4* p = (const float4*)(in + i * 8);
    float4 a = p[0], b = p[1];
    *(uint4*)(out + i * 8) = pack8(a, b);
}

// ---------- GEMM: C[M,N] = A_bf16[M,K] * Bt_bf16[N,K]^T + bias_f32 --------------
// m97 structure, BK=64 (16 sync-iters instead of 32). Tiles staged with
// global_load_lds width-16; rule-21 both-sides XOR swizzle (byte^=((row&7)<<4))
// keeps the 128B-row frag reads bank-conflict-free. XCD-aware block swizzle (T1).
// mode 0: scatter bf16 into q/k [B,H,S,DH] and V TRANSPOSED [B,H,DH,S]
// mode 1: write f32 outf [M,N]
__global__ __launch_bounds__(256) void gemm_bt(const unsigned short* __restrict__ A,
                                               const unsigned short* __restrict__ Bt,
                                               const float* __restrict__ bias,
                                               int mode,
                                               unsigned short* __restrict__ qo,
                                               unsigned short* __restrict__ ko,
                                               unsigned short* __restrict__ vo,
                                               float* __restrict__ outf) {
    __shared__ __align__(16) unsigned short As[128 * 64];   // [m][k] swizzled, 128B rows
    __shared__ __align__(16) unsigned short Bs[128 * 64];   // [n][k] swizzled
    const int tid = threadIdx.x;
    const int wave = tid >> 6, lane = tid & 63, g = lane >> 4, ln = lane & 15;
    const int wm = wave >> 1, wn = wave & 1;          // 2x2 wave grid, 64x64 each
    // T1: bijective XCD swizzle (nwg = 1536 or 512, both % 8 == 0)
    const int nwg = gridDim.x * gridDim.y;
    const int orig = blockIdx.y * gridDim.x + blockIdx.x;
    const int swz = (orig & 7) * (nwg >> 3) + (orig >> 3);
    const int m0 = (swz / gridDim.x) * 128, n0 = (swz % gridDim.x) * 128;

    f32x4 acc[4][4];
    for (int i = 0; i < 4; i++)
        for (int j = 0; j < 4; j++) acc[i][j] = f32x4{0.f, 0.f, 0.f, 0.f};

    for (int k0 = 0; k0 < Kdim; k0 += 64) {
#pragma unroll
        for (int c = 0; c < 4; c++) {
            int L = c * 4096 + tid * 16;              // byte within 16KB operand tile
            int row = L >> 7;                         // 128B per row (64 bf16)
            int colb = (L & 127) ^ ((row & 7) << 4);  // inverse-swizzled source col
            gl16((const char*)A  + ((size_t)(m0 + row) * Kdim + k0) * 2 + colb,
                 (char*)As + c * 4096 + wave * 1024);
            gl16((const char*)Bt + ((size_t)(n0 + row) * Kdim + k0) * 2 + colb,
                 (char*)Bs + c * 4096 + wave * 1024);
        }
        __syncthreads();                               // drains vmcnt(0) + barrier
#pragma unroll
        for (int kk = 0; kk < 2; kk++) {
            bf16x8 af[4], bfr[4];
#pragma unroll
            for (int t = 0; t < 4; t++) {
                int ra = wm * 64 + t * 16 + ln;
                int rb = wn * 64 + t * 16 + ln;
                int co = kk * 64 + g * 16;
                af[t]  = ld8((const unsigned short*)((const char*)As + ra * 128 + (co ^ ((ra & 7) << 4))));
                bfr[t] = ld8((const unsigned short*)((const char*)Bs + rb * 128 + (co ^ ((rb & 7) << 4))));
            }
#pragma unroll
            for (int mt = 0; mt < 4; mt++)
#pragma unroll
                for (int nt = 0; nt < 4; nt++)
                    acc[mt][nt] = __builtin_amdgcn_mfma_f32_16x16x32_bf16(af[mt], bfr[nt], acc[mt][nt], 0, 0, 0);
        }
        __syncthreads();
    }

    // epilogue: C/D layout col=lane&15, row=(lane>>4)*4+reg (round-1 proven form;
    // L2 write-back coalesces the V^T 2B scatter: measured WRITE ~= ideal)
    for (int mt = 0; mt < 4; mt++)
        for (int nt = 0; nt < 4; nt++)
            for (int r = 0; r < 4; r++) {
                int m = m0 + wm * 64 + mt * 16 + g * 4 + r;
                int n = n0 + wn * 64 + nt * 16 + ln;
                float val = acc[mt][nt][r] + bias[n];
                if (mode == 0) {
                    int which = n >> 10, rem = n & 1023;
                    int hh = rem >> 6, dd = rem & 63;
                    int b = m >> 11, s = m & 2047;
                    int bh = (b << 4) + hh;
                    if (which == 0)      qo[((size_t)bh * S + s) * DH + dd] = f2bf(val);
                    else if (which == 1) ko[((size_t)bh * S + s) * DH + dd] = f2bf(val);
                    else                 vo[((size_t)bh * DH + dd) * S + s] = f2bf(val);  // V^T
                } else {
                    outf[(size_t)m * 1024 + n] = val;
                }
            }
}

// ---------- flash attention (round-1 proven form): global_load_lds staging ------
// Linear LDS tiles + rule-21 XOR swizzle: inverse-swizzled GLOBAL source address,
// same XOR applied on ds_read. K [128][64] swz byte^=((row&7)<<4);
// V^T [64][128] swz byte^=((row&15)<<4).
__global__ __launch_bounds__(256, 3) void attn_fwd(const unsigned short* __restrict__ qg,
                                                   const unsigned short* __restrict__ kg,
                                                   const unsigned short* __restrict__ vtg,
                                                   unsigned short* __restrict__ og) {
    __shared__ __align__(16) unsigned short Ks[128 * 64];  // [kv][dh] swizzled
    __shared__ __align__(16) unsigned short Vs[64 * 128];  // [dh][kv] swizzled
    __shared__ __align__(16) unsigned short P [64 * 136];  // probs [q][kv], wave-private rows
    const int idx = blockIdx.x;
    const int qt = 31 - (idx >> 6);                        // heavy tiles dispatch first
    const int bh = idx & 63;                               // idx%8 = bh%8 -> same-bh same XCD
    const int b = bh >> 4, h = bh & 15;
    const size_t base = (size_t)bh * S * DH;
    const unsigned short* qp = qg + base;
    const char* kpb  = (const char*)(kg  + base);
    const char* vtpb = (const char*)(vtg + base);          // [DH][S] bytes: row stride 4096
    const int tid = threadIdx.x, wave = tid >> 6, lane = tid & 63;
    const int g = lane >> 4, ln = lane & 15;
    const int q0 = qt * 64, wq = wave * 16;                // wave's q rows [q0+wq, +16)
    const int jn = (qt >> 1) + 1;

    // Q B-frag (B-layout: n=ln -> q=q0+wq+ln; k=kc*32+g*8+j)
    bf16x8 qf[2];
    qf[0] = ld8(qp + (size_t)(q0 + wq + ln) * DH + g * 8);
    qf[1] = ld8(qp + (size_t)(q0 + wq + ln) * DH + 32 + g * 8);

    f32x4 o_t[4];
#pragma unroll
    for (int dt = 0; dt < 4; dt++) o_t[dt] = f32x4{0.f, 0.f, 0.f, 0.f};
    float m_ = -1e30f, l_ = 0.f;

#pragma unroll 1
    for (int j = 0; j < jn; j++) {
        // ---- stage tile j direct to LDS (16KB K + 16KB V, 4KB per issue)
        const char* kj = kpb + (size_t)j * (128 * DH * 2);
        const char* vj = vtpb + j * 256;
#pragma unroll
        for (int c = 0; c < 4; c++) {
            int L = c * 4096 + tid * 16;
            int kr = L >> 7, kcb = L & 127;                // K: 128B rows
            gl16(kj + (size_t)kr * 128 + (kcb ^ ((kr & 7) << 4)),
                 (char*)Ks + c * 4096 + wave * 1024);
            int vr = L >> 8, vcb = L & 255;                // V^T: 256B rows in tile
            gl16(vj + (size_t)vr * 4096 + (vcb ^ ((vr & 15) << 4)),
                 (char*)Vs + c * 4096 + wave * 1024);
        }
        __syncthreads();   // drains vmcnt(0) then barrier: all waves' tiles visible

        // ---- S^T = K*Q^T : st[mt] C-layout kv=mt*16+g*4+r, q-col=ln
        f32x4 st[8];
#pragma unroll
        for (int mt = 0; mt < 8; mt++) {
            int row = mt * 16 + ln;
            int sw = (row & 7) << 4;
            const char* kb2 = (const char*)Ks + row * 128;
            bf16x8 kf0 = ld8((const unsigned short*)(kb2 + ((g * 16) ^ sw)));
            bf16x8 kf1 = ld8((const unsigned short*)(kb2 + ((64 + g * 16) ^ sw)));
            f32x4 t = f32x4{0.f, 0.f, 0.f, 0.f};
            t = __builtin_amdgcn_mfma_f32_16x16x32_bf16(kf0, qf[0], t, 0, 0, 0);
            t = __builtin_amdgcn_mfma_f32_16x16x32_bf16(kf1, qf[1], t, 0, 0, 0);
            st[mt] = t;
        }
        if (j == jn - 1) {   // diagonal: mask kv_global > q_global
            int qgl = q0 + wq + ln;
#pragma unroll
            for (int mt = 0; mt < 8; mt++)
#pragma unroll
                for (int r = 0; r < 4; r++) {
                    int kvg = j * 128 + mt * 16 + g * 4 + r;
                    if (kvg > qgl) st[mt][r] = -3e38f;
                }
        }
        // ---- online softmax: q = ln is lane-resident; kv spread over (g, mt, r)
        f32x4 mm = st[0];
#pragma unroll
        for (int mt = 1; mt < 8; mt++)
#pragma unroll
            for (int e = 0; e < 4; e++) mm[e] = fmaxf(mm[e], st[mt][e]);
        float mx = fmaxf(fmaxf(mm[0], mm[1]), fmaxf(mm[2], mm[3]));
        mx = fmaxf(mx, __shfl_xor(mx, 16));
        mx = fmaxf(mx, __shfl_xor(mx, 32));
        float mnew = fmaxf(m_, mx);
        float alpha = __expf((m_ - mnew) * 0.125f);
        f32x4 sv = f32x4{0.f, 0.f, 0.f, 0.f};
#pragma unroll
        for (int mt = 0; mt < 8; mt++) {
            f32x4 pr;
#pragma unroll
            for (int e = 0; e < 4; e++) pr[e] = __expf((st[mt][e] - mnew) * 0.125f);
            st[mt] = pr;
            sv += pr;
        }
        float rs = (sv[0] + sv[1]) + (sv[2] + sv[3]);
        rs += __shfl_xor(rs, 16);
        rs += __shfl_xor(rs, 32);
        l_ = l_ * alpha + rs;
        m_ = mnew;

        // ---- pack P (truncate f32->bf16) into [q][kv] rows (wave-private)
#pragma unroll
        for (int mt = 0; mt < 8; mt++) {
            uint4 u = __builtin_bit_cast(uint4, st[mt]);
            uint2 w;
            w.x = (u.y & 0xFFFF0000u) | (u.x >> 16);
            w.y = (u.w & 0xFFFF0000u) | (u.z >> 16);
            *(uint2*)&P[(wq + ln) * 136 + mt * 16 + g * 4] = w;
        }
        // ---- rescale O^T (cols = q = ln)
#pragma unroll
        for (int dt = 0; dt < 4; dt++) o_t[dt] *= alpha;

        // ---- O^T += V^T * P^T (A = V^T from swizzled LDS, B = P^T from wave rows)
#pragma unroll
        for (int kc = 0; kc < 4; kc++) {
            bf16x8 pf = ld8(&P[(wq + ln) * 136 + kc * 32 + g * 8]);
            bf16x8 vf[4];
#pragma unroll
            for (int dt = 0; dt < 4; dt++) {
                int row = dt * 16 + ln;
                vf[dt] = ld8((const unsigned short*)((const char*)Vs + row * 256 +
                             ((kc * 64 + g * 16) ^ ((row & 15) << 4))));
            }
#pragma unroll
            for (int dt = 0; dt < 4; dt++)
                o_t[dt] = __builtin_amdgcn_mfma_f32_16x16x32_bf16(vf[dt], pf, o_t[dt], 0, 0, 0);
        }
        __syncthreads();   // all waves done reading Ks/Vs before next overwrite
    }

    // ---- epilogue: scale 1/l, transpose O^T via wave-private LDS, bf16 stores.
    float il = 1.f / l_;
#pragma unroll
    for (int dt = 0; dt < 4; dt++) o_t[dt] *= il;
    float* Ot = (float*)&P[wq * 136];
#pragma unroll
    for (int dt = 0; dt < 4; dt++)
        *(float4*)&Ot[ln * 68 + dt * 16 + g * 4] =
            float4{o_t[dt][0], o_t[dt][1], o_t[dt][2], o_t[dt][3]};
    // same-wave LDS RAW: DS ops are in-order per wave
#pragma unroll
    for (int i = 0; i < 4; i++) {
        float4 v = *(float4*)&Ot[(i * 4 + g) * 68 + ln * 4];
        uint2 w;
        w.x = (uint32_t)f2bf(v.x) | ((uint32_t)f2bf(v.y) << 16);
        w.y = (uint32_t)f2bf(v.z) | ((uint32_t)f2bf(v.w) << 16);
        *(uint2*)&og[((size_t)(b * S + q0 + wq + i * 4 + g)) * D + h * DH + ln * 4] = w;
    }
}

extern "C" void kernel_launch(void* const* d_in, const int* in_sizes, int n_in,
                              void* d_out, int out_size, void* d_ws, size_t ws_size,
                              hipStream_t stream) {
    (void)in_sizes; (void)n_in; (void)out_size; (void)ws_size;
    const float* x      = (const float*)d_in[0];  // [B,S,D] f32
    const float* w_attn = (const float*)d_in[1];  // [D,3D]  f32
    const float* b_attn = (const float*)d_in[2];  // [3D]    f32
    const float* w_proj = (const float*)d_in[3];  // [D,D]   f32
    const float* b_proj = (const float*)d_in[4];  // [D]     f32

    char* ws = (char*)d_ws;
    unsigned short* wattn_t = (unsigned short*)ws;                 // [3072][1024] bf16
    unsigned short* wproj_t = (unsigned short*)(ws + 6291456);     // [1024][1024] bf16
    unsigned short* xb      = (unsigned short*)(ws + 8388608);     // [B*S][D] bf16
    unsigned short* qb      = (unsigned short*)(ws + 25165824);    // [B,H,S,DH] bf16
    unsigned short* kb      = (unsigned short*)(ws + 41943040);
    unsigned short* vtb     = (unsigned short*)(ws + 58720256);    // [B,H,DH,S] bf16
    unsigned short* aob     = (unsigned short*)(ws + 75497472);    // [B,S,D] bf16

    transpose_cvt<<<dim3(96, 32), 256, 0, stream>>>(w_attn, wattn_t, 1024, 3072);
    transpose_cvt<<<dim3(32, 32), 256, 0, stream>>>(w_proj, wproj_t, 1024, 1024);
    cvt_bf16<<<dim3(4096), 256, 0, stream>>>(x, xb);
    gemm_bt<<<dim3(24, 64), 256, 0, stream>>>(xb, wattn_t, b_attn, 0, qb, kb, vtb, nullptr);
    attn_fwd<<<dim3(2048), 256, 0, stream>>>(qb, kb, vtb, aob);
    gemm_bt<<<dim3(8, 64), 256, 0, stream>>>(aob, wproj_t, b_proj, 1,
                                             nullptr, nullptr, nullptr, (float*)d_out);
}

// Round 4
// 264.533 us; speedup vs baseline: 1.2990x; 1.0738x over previous
//
#include <hip/hip_runtime.h>
#include <stdint.h>

typedef __bf16 bf16x8 __attribute__((ext_vector_type(8)));
typedef float  f32x4  __attribute__((ext_vector_type(4)));

#define DEV __device__ __forceinline__

constexpr int Bc = 4, S = 2048, D = 1024, Hh = 16, DH = 64;
constexpr int Kdim = 1024;   // inner K of both GEMMs

DEV unsigned short f2bf(float f) {
    uint32_t u = __builtin_bit_cast(uint32_t, f);
    u += 0x7fff + ((u >> 16) & 1);   // RNE
    return (unsigned short)(u >> 16);
}
DEV bf16x8 ld8(const unsigned short* p) {
    uint4 u = *(const uint4*)p;
    return __builtin_bit_cast(bf16x8, u);
}
DEV uint4 pack8(float4 a, float4 b) {
    union { uint4 u; unsigned short s[8]; } r;
    r.s[0] = f2bf(a.x); r.s[1] = f2bf(a.y); r.s[2] = f2bf(a.z); r.s[3] = f2bf(a.w);
    r.s[4] = f2bf(b.x); r.s[5] = f2bf(b.y); r.s[6] = f2bf(b.z); r.s[7] = f2bf(b.w);
    return r.u;
}

// async global->LDS, 16B per lane. LDS dest is wave-uniform base + lane*16 (HW).
DEV void gl16(const void* g, void* l) {
    __builtin_amdgcn_global_load_lds((__attribute__((address_space(1))) void*)g,
                                     (__attribute__((address_space(3))) void*)l,
                                     16, 0, 0);
}

// ---------- weight transpose + cvt (f32 [rows][cols] -> bf16 [cols][rows]) ------
__global__ __launch_bounds__(256) void transpose_cvt(const float* __restrict__ in,
                                                     unsigned short* __restrict__ out,
                                                     int rows, int cols) {
    __shared__ float t[32][33];
    int tx = threadIdx.x & 31, ty = threadIdx.x >> 5;  // 32 x 8
    int c = blockIdx.x * 32 + tx;
    int rbase = blockIdx.y * 32;
    for (int rr = 0; rr < 32; rr += 8)
        t[ty + rr][tx] = in[(size_t)(rbase + ty + rr) * cols + c];
    __syncthreads();
    int orbase = blockIdx.x * 32;
    for (int rr = 0; rr < 32; rr += 8)
        out[(size_t)(orbase + ty + rr) * rows + rbase + tx] = f2bf(t[tx][ty + rr]);
}

// ---------- x f32 -> bf16, once --------------------------------------------------
__global__ __launch_bounds__(256) void cvt_bf16(const float* __restrict__ in,
                                                unsigned short* __restrict__ out) {
    size_t i = (size_t)blockIdx.x * 256 + threadIdx.x;   // 8 elems per thread, exact grid
    const float4* p = (const float4*)(in + i * 8);
    float4 a = p[0], b = p[1];
    *(uint4*)(out + i * 8) = pack8(a, b);
}

// ---------- GEMM: C[M,N] = A_bf16[M,K] * Bt_bf16[N,K]^T + bias_f32 --------------
// T3-minimum 2-phase: double-buffered BK=64 tiles staged with global_load_lds,
// STAGE(next) issued BEFORE computing current, then vmcnt(0) (hidden under the
// 32 MFMA + 16 ds_read of the current tile) + ONE s_barrier per K-step.
// Rule-21 both-sides XOR swizzle (byte^=((row&7)<<4)) -> 0 bank conflicts (R3).
// XCD-aware bijective block swizzle (T1).
// mode 0: scatter bf16 into q/k [B,H,S,DH] and V TRANSPOSED [B,H,DH,S]
// mode 1: write f32 outf [M,N]
__global__ __launch_bounds__(256) void gemm_bt(const unsigned short* __restrict__ A,
                                               const unsigned short* __restrict__ Bt,
                                               const float* __restrict__ bias,
                                               int mode,
                                               unsigned short* __restrict__ qo,
                                               unsigned short* __restrict__ ko,
                                               unsigned short* __restrict__ vo,
                                               float* __restrict__ outf) {
    __shared__ __align__(16) unsigned short As[2][128 * 64];   // [m][k] swizzled, 128B rows
    __shared__ __align__(16) unsigned short Bs[2][128 * 64];   // [n][k] swizzled   (64KB total)
    const int tid = threadIdx.x;
    const int wave = tid >> 6, lane = tid & 63, g = lane >> 4, ln = lane & 15;
    const int wm = wave >> 1, wn = wave & 1;          // 2x2 wave grid, 64x64 each
    // T1: bijective XCD swizzle (nwg = 1536 or 512, both % 8 == 0)
    const int nwg = gridDim.x * gridDim.y;
    const int orig = blockIdx.y * gridDim.x + blockIdx.x;
    const int swz = (orig & 7) * (nwg >> 3) + (orig >> 3);
    const int m0 = (swz / gridDim.x) * 128, n0 = (swz % gridDim.x) * 128;

    f32x4 acc[4][4];
    for (int i = 0; i < 4; i++)
        for (int j = 0; j < 4; j++) acc[i][j] = f32x4{0.f, 0.f, 0.f, 0.f};

    // stage one K-tile (8 gl16/thread) into buffer `buf`, inverse-swizzled source
#define STAGE_G(buf, k0)                                                            \
    _Pragma("unroll")                                                               \
    for (int c = 0; c < 4; c++) {                                                   \
        int L = c * 4096 + tid * 16;                                                \
        int row = L >> 7;                                                           \
        int colb = (L & 127) ^ ((row & 7) << 4);                                    \
        gl16((const char*)A  + ((size_t)(m0 + row) * Kdim + (k0)) * 2 + colb,       \
             (char*)As[buf] + c * 4096 + wave * 1024);                              \
        gl16((const char*)Bt + ((size_t)(n0 + row) * Kdim + (k0)) * 2 + colb,       \
             (char*)Bs[buf] + c * 4096 + wave * 1024);                              \
    }

    STAGE_G(0, 0);
    asm volatile("s_waitcnt vmcnt(0)" ::: "memory");
    __builtin_amdgcn_s_barrier();
    asm volatile("" ::: "memory");

#pragma unroll 1
    for (int t = 0; t < 16; t++) {
        const int buf = t & 1;
        if (t + 1 < 16) STAGE_G(buf ^ 1, (t + 1) * 64);    // next tile in flight
        const unsigned short* Asb = As[buf];
        const unsigned short* Bsb = Bs[buf];
#pragma unroll
        for (int kk = 0; kk < 2; kk++) {
            bf16x8 af[4], bfr[4];
#pragma unroll
            for (int u = 0; u < 4; u++) {
                int ra = wm * 64 + u * 16 + ln;
                int rb = wn * 64 + u * 16 + ln;
                int co = kk * 64 + g * 16;
                af[u]  = ld8((const unsigned short*)((const char*)Asb + ra * 128 + (co ^ ((ra & 7) << 4))));
                bfr[u] = ld8((const unsigned short*)((const char*)Bsb + rb * 128 + (co ^ ((rb & 7) << 4))));
            }
#pragma unroll
            for (int mt = 0; mt < 4; mt++)
#pragma unroll
                for (int nt = 0; nt < 4; nt++)
                    acc[mt][nt] = __builtin_amdgcn_mfma_f32_16x16x32_bf16(af[mt], bfr[nt], acc[mt][nt], 0, 0, 0);
        }
        asm volatile("" ::: "memory");
        asm volatile("s_waitcnt vmcnt(0)" ::: "memory");   // next tile landed (flew under compute)
        __builtin_amdgcn_s_barrier();                      // reads done + deposits visible
        asm volatile("" ::: "memory");
    }
#undef STAGE_G

    // epilogue: C/D layout col=lane&15, row=(lane>>4)*4+reg (R1-proven scatter;
    // L2 write-back coalesces the V^T 2B scatter: measured WRITE ~= ideal)
    for (int mt = 0; mt < 4; mt++)
        for (int nt = 0; nt < 4; nt++)
            for (int r = 0; r < 4; r++) {
                int m = m0 + wm * 64 + mt * 16 + g * 4 + r;
                int n = n0 + wn * 64 + nt * 16 + ln;
                float val = acc[mt][nt][r] + bias[n];
                if (mode == 0) {
                    int which = n >> 10, rem = n & 1023;
                    int hh = rem >> 6, dd = rem & 63;
                    int b = m >> 11, s = m & 2047;
                    int bh = (b << 4) + hh;
                    if (which == 0)      qo[((size_t)bh * S + s) * DH + dd] = f2bf(val);
                    else if (which == 1) ko[((size_t)bh * S + s) * DH + dd] = f2bf(val);
                    else                 vo[((size_t)bh * DH + dd) * S + s] = f2bf(val);  // V^T
                } else {
                    outf[(size_t)m * 1024 + n] = val;
                }
            }
}

// ---------- flash attention: QBLK=128, 8 waves/block (R3 inner structure) -------
// K/V staged once per 128 q-rows instead of 64 -> staging bytes, drain events and
// barrier totals all halve; occupancy 12 -> 16 waves/CU (LDS 67.6KB, 2 blk/CU).
// Linear LDS tiles + rule-21 XOR swizzle: inverse-swizzled GLOBAL source address,
// same XOR applied on ds_read. K [128][64] swz byte^=((row&7)<<4);
// V^T [64][128] swz byte^=((row&15)<<4).
__global__ __launch_bounds__(512, 4) void attn_fwd(const unsigned short* __restrict__ qg,
                                                   const unsigned short* __restrict__ kg,
                                                   const unsigned short* __restrict__ vtg,
                                                   unsigned short* __restrict__ og) {
    __shared__ __align__(16) unsigned short Ks[128 * 64];  // [kv][dh] swizzled
    __shared__ __align__(16) unsigned short Vs[64 * 128];  // [dh][kv] swizzled
    __shared__ __align__(16) unsigned short P [128 * 136]; // probs [q][kv], wave-private rows
    const int idx = blockIdx.x;
    const int qt = 15 - (idx >> 6);                        // heavy tiles dispatch first
    const int bh = idx & 63;                               // idx%8 = bh%8 -> same-bh same XCD
    const int b = bh >> 4, h = bh & 15;
    const size_t base = (size_t)bh * S * DH;
    const unsigned short* qp = qg + base;
    const char* kpb  = (const char*)(kg  + base);
    const char* vtpb = (const char*)(vtg + base);          // [DH][S] bytes: row stride 4096
    const int tid = threadIdx.x, wave = tid >> 6, lane = tid & 63;
    const int g = lane >> 4, ln = lane & 15;
    const int q0 = qt * 128, wq = wave * 16;               // wave's q rows [q0+wq, +16)
    const int jn = qt + 1;

    // Q B-frag (B-layout: n=ln -> q=q0+wq+ln; k=kc*32+g*8+j)
    bf16x8 qf[2];
    qf[0] = ld8(qp + (size_t)(q0 + wq + ln) * DH + g * 8);
    qf[1] = ld8(qp + (size_t)(q0 + wq + ln) * DH + 32 + g * 8);

    f32x4 o_t[4];
#pragma unroll
    for (int dt = 0; dt < 4; dt++) o_t[dt] = f32x4{0.f, 0.f, 0.f, 0.f};
    float m_ = -1e30f, l_ = 0.f;

#pragma unroll 1
    for (int j = 0; j < jn; j++) {
        // ---- stage tile j direct to LDS (16KB K + 16KB V; 512 thr * 16B * 2)
        const char* kj = kpb + (size_t)j * (128 * DH * 2);
        const char* vj = vtpb + j * 256;
#pragma unroll
        for (int c = 0; c < 2; c++) {
            int L = c * 8192 + tid * 16;
            int kr = L >> 7, kcb = L & 127;                // K: 128B rows
            gl16(kj + (size_t)kr * 128 + (kcb ^ ((kr & 7) << 4)),
                 (char*)Ks + c * 8192 + wave * 1024);
            int vr = L >> 8, vcb = L & 255;                // V^T: 256B rows in tile
            gl16(vj + (size_t)vr * 4096 + (vcb ^ ((vr & 15) << 4)),
                 (char*)Vs + c * 8192 + wave * 1024);
        }
        __syncthreads();   // drains vmcnt(0) then barrier: all waves' tiles visible

        // ---- S^T = K*Q^T : st[mt] C-layout kv=mt*16+g*4+r, q-col=ln
        f32x4 st[8];
#pragma unroll
        for (int mt = 0; mt < 8; mt++) {
            int row = mt * 16 + ln;
            int sw = (row & 7) << 4;
            const char* kb2 = (const char*)Ks + row * 128;
            bf16x8 kf0 = ld8((const unsigned short*)(kb2 + ((g * 16) ^ sw)));
            bf16x8 kf1 = ld8((const unsigned short*)(kb2 + ((64 + g * 16) ^ sw)));
            f32x4 t = f32x4{0.f, 0.f, 0.f, 0.f};
            t = __builtin_amdgcn_mfma_f32_16x16x32_bf16(kf0, qf[0], t, 0, 0, 0);
            t = __builtin_amdgcn_mfma_f32_16x16x32_bf16(kf1, qf[1], t, 0, 0, 0);
            st[mt] = t;
        }
        if (j == jn - 1) {   // diagonal: mask kv_global > q_global
            int qgl = q0 + wq + ln;
#pragma unroll
            for (int mt = 0; mt < 8; mt++)
#pragma unroll
                for (int r = 0; r < 4; r++) {
                    int kvg = j * 128 + mt * 16 + g * 4 + r;
                    if (kvg > qgl) st[mt][r] = -3e38f;
                }
        }
        // ---- online softmax: q = ln is lane-resident; kv spread over (g, mt, r)
        f32x4 mm = st[0];
#pragma unroll
        for (int mt = 1; mt < 8; mt++)
#pragma unroll
            for (int e = 0; e < 4; e++) mm[e] = fmaxf(mm[e], st[mt][e]);
        float mx = fmaxf(fmaxf(mm[0], mm[1]), fmaxf(mm[2], mm[3]));
        mx = fmaxf(mx, __shfl_xor(mx, 16));
        mx = fmaxf(mx, __shfl_xor(mx, 32));
        float mnew = fmaxf(m_, mx);
        float alpha = __expf((m_ - mnew) * 0.125f);
        f32x4 sv = f32x4{0.f, 0.f, 0.f, 0.f};
#pragma unroll
        for (int mt = 0; mt < 8; mt++) {
            f32x4 pr;
#pragma unroll
            for (int e = 0; e < 4; e++) pr[e] = __expf((st[mt][e] - mnew) * 0.125f);
            st[mt] = pr;
            sv += pr;
        }
        float rs = (sv[0] + sv[1]) + (sv[2] + sv[3]);
        rs += __shfl_xor(rs, 16);
        rs += __shfl_xor(rs, 32);
        l_ = l_ * alpha + rs;
        m_ = mnew;

        // ---- pack P (truncate f32->bf16) into [q][kv] rows (wave-private)
#pragma unroll
        for (int mt = 0; mt < 8; mt++) {
            uint4 u = __builtin_bit_cast(uint4, st[mt]);
            uint2 w;
            w.x = (u.y & 0xFFFF0000u) | (u.x >> 16);
            w.y = (u.w & 0xFFFF0000u) | (u.z >> 16);
            *(uint2*)&P[(wq + ln) * 136 + mt * 16 + g * 4] = w;
        }
        // ---- rescale O^T (cols = q = ln)
#pragma unroll
        for (int dt = 0; dt < 4; dt++) o_t[dt] *= alpha;

        // ---- O^T += V^T * P^T (A = V^T from swizzled LDS, B = P^T from wave rows)
#pragma unroll
        for (int kc = 0; kc < 4; kc++) {
            bf16x8 pf = ld8(&P[(wq + ln) * 136 + kc * 32 + g * 8]);
            bf16x8 vf[4];
#pragma unroll
            for (int dt = 0; dt < 4; dt++) {
                int row = dt * 16 + ln;
                vf[dt] = ld8((const unsigned short*)((const char*)Vs + row * 256 +
                             ((kc * 64 + g * 16) ^ ((row & 15) << 4))));
            }
#pragma unroll
            for (int dt = 0; dt < 4; dt++)
                o_t[dt] = __builtin_amdgcn_mfma_f32_16x16x32_bf16(vf[dt], pf, o_t[dt], 0, 0, 0);
        }
        __syncthreads();   // all waves done reading Ks/Vs before next overwrite
    }

    // ---- epilogue: scale 1/l, transpose O^T via wave-private LDS, bf16 stores.
    //      Wave region = P rows [wq..wq+16) = [16][68] f32 (4352B, exact fit).
    float il = 1.f / l_;
#pragma unroll
    for (int dt = 0; dt < 4; dt++) o_t[dt] *= il;
    float* Ot = (float*)&P[wq * 136];
#pragma unroll
    for (int dt = 0; dt < 4; dt++)
        *(float4*)&Ot[ln * 68 + dt * 16 + g * 4] =
            float4{o_t[dt][0], o_t[dt][1], o_t[dt][2], o_t[dt][3]};
    // same-wave LDS RAW: DS ops are in-order per wave
#pragma unroll
    for (int i = 0; i < 4; i++) {
        float4 v = *(float4*)&Ot[(i * 4 + g) * 68 + ln * 4];
        uint2 w;
        w.x = (uint32_t)f2bf(v.x) | ((uint32_t)f2bf(v.y) << 16);
        w.y = (uint32_t)f2bf(v.z) | ((uint32_t)f2bf(v.w) << 16);
        *(uint2*)&og[((size_t)(b * S + q0 + wq + i * 4 + g)) * D + h * DH + ln * 4] = w;
    }
}

extern "C" void kernel_launch(void* const* d_in, const int* in_sizes, int n_in,
                              void* d_out, int out_size, void* d_ws, size_t ws_size,
                              hipStream_t stream) {
    (void)in_sizes; (void)n_in; (void)out_size; (void)ws_size;
    const float* x      = (const float*)d_in[0];  // [B,S,D] f32
    const float* w_attn = (const float*)d_in[1];  // [D,3D]  f32
    const float* b_attn = (const float*)d_in[2];  // [3D]    f32
    const float* w_proj = (const float*)d_in[3];  // [D,D]   f32
    const float* b_proj = (const float*)d_in[4];  // [D]     f32

    char* ws = (char*)d_ws;
    unsigned short* wattn_t = (unsigned short*)ws;                 // [3072][1024] bf16
    unsigned short* wproj_t = (unsigned short*)(ws + 6291456);     // [1024][1024] bf16
    unsigned short* xb      = (unsigned short*)(ws + 8388608);     // [B*S][D] bf16
    unsigned short* qb      = (unsigned short*)(ws + 25165824);    // [B,H,S,DH] bf16
    unsigned short* kb      = (unsigned short*)(ws + 41943040);
    unsigned short* vtb     = (unsigned short*)(ws + 58720256);    // [B,H,DH,S] bf16
    unsigned short* aob     = (unsigned short*)(ws + 75497472);    // [B,S,D] bf16

    transpose_cvt<<<dim3(96, 32), 256, 0, stream>>>(w_attn, wattn_t, 1024, 3072);
    transpose_cvt<<<dim3(32, 32), 256, 0, stream>>>(w_proj, wproj_t, 1024, 1024);
    cvt_bf16<<<dim3(4096), 256, 0, stream>>>(x, xb);
    gemm_bt<<<dim3(24, 64), 256, 0, stream>>>(xb, wattn_t, b_attn, 0, qb, kb, vtb, nullptr);
    attn_fwd<<<dim3(1024), 512, 0, stream>>>(qb, kb, vtb, aob);
    gemm_bt<<<dim3(8, 64), 256, 0, stream>>>(aob, wproj_t, b_proj, 1,
                                             nullptr, nullptr, nullptr, (float*)d_out);
}